// Round 6
// baseline (145.700 us; speedup 1.0000x reference)
//
#include <hip/hip_runtime.h>

#define S_CONST 8
#define K_CONST 10
#define EPSF 1e-8f
#define MAXBLK 4080   // 4080*16B partials + 4B counter = 65284 <= 65536 (proven ws)

struct Samp { int y; int a1[S_CONST]; int a2[S_CONST]; };

__device__ __forceinline__ void load_samp(Samp& sm, const int* __restrict__ Y,
                                          const int* __restrict__ s1g,
                                          const int* __restrict__ s2g,
                                          int B, int row, bool inb) {
    if (inb) {
        sm.y = Y[row];
        #pragma unroll
        for (int s = 0; s < S_CONST; ++s) {
            sm.a1[s] = s1g[(size_t)s * B + row];
            sm.a2[s] = s2g[(size_t)s * B + row];
        }
    } else {
        sm.y = -1;
        #pragma unroll
        for (int s = 0; s < S_CONST; ++s) { sm.a1[s] = 0; sm.a2[s] = 0; }
    }
}

__device__ __forceinline__ void load_pcs(const float* __restrict__ pCS, int base, int B,
                                         bool full, float4 v[5], int lane) {
    const float4* src = reinterpret_cast<const float4*>(pCS + (size_t)base * 20);
    #pragma unroll
    for (int k = 0; k < 5; ++k) {
        const int g = lane + (k << 6);
        float4 t = make_float4(1.f, 1.f, 1.f, 1.f);    // log(1)=0 padding (tail only)
        if (full || (base + g / 5) < B) t = src[g];
        v[k] = t;
    }
}

// entropy from registers + write LOG panel (rloo gathers logs directly)
__device__ __forceinline__ float ent_write(float* __restrict__ pan,
                                           const float4 v[5], int lane) {
    float e = 0.f;
    float4* dst = reinterpret_cast<float4*>(pan);
    #pragma unroll
    for (int k = 0; k < 5; ++k) {
        float4 lg;
        lg.x = __logf(v[k].x); lg.y = __logf(v[k].y);
        lg.z = __logf(v[k].z); lg.w = __logf(v[k].w);
        e += v[k].x * lg.x + v[k].y * lg.y + v[k].z * lg.z + v[k].w * lg.w;
        dst[lane + (k << 6)] = lg;                      // ds_write_b128
    }
    return e;
}

__device__ __forceinline__ void body(const float* __restrict__ pan, const Samp& sm,
                                     bool inb, int lane,
                                     float& uniq, float& corr, float& rloo) {
    if (!inb) return;
    int pr[S_CONST]; float c[S_CONST];
    float csum = 0.f;
    #pragma unroll
    for (int s = 0; s < S_CONST; ++s) {
        pr[s] = sm.a1[s] * K_CONST + sm.a2[s];
        c[s]  = (sm.a1[s] + sm.a2[s] == sm.y) ? 1.f : 0.f;
        csum += c[s];
    }
    corr += csum;

    #pragma unroll
    for (int i = 0; i < S_CONST; ++i) {
        bool dup = false;
        #pragma unroll
        for (int j = 0; j < i; ++j) dup = dup || (pr[i] == pr[j]);
        uniq += dup ? 0.f : 1.f;
    }

    const float* my = &pan[lane * 20];
    const float cs7 = csum * (1.0f / 7.0f);
    #pragma unroll
    for (int s = 0; s < S_CONST; ++s) {
        const float lp = my[sm.a1[s]] + my[10 + sm.a2[s]];   // gathered logs
        const float adv = c[s] * (8.0f / 7.0f) - cs7;        // c - (csum-c)/7
        rloo += lp * adv;
    }
}

// process one 64-row chunk given preloaded pCS regs + samples
__device__ __forceinline__ void chunk(float* pan, const float4 v[5], const Samp& sm,
                                      bool has, bool inb, int lane,
                                      float& ent, float& uniq, float& corr, float& rloo) {
    if (has) ent += ent_write(pan, v, lane);
    __builtin_amdgcn_wave_barrier();
    body(pan, sm, inb, lane, uniq, corr, rloo);
    __builtin_amdgcn_wave_barrier();
}

__global__ __launch_bounds__(128) void fml_fused(
        const float* __restrict__ pCS,
        const int* __restrict__ Y,
        const int* __restrict__ s1g,
        const int* __restrict__ s2g,
        const float* __restrict__ base_loss,
        float* __restrict__ out,
        float4* __restrict__ partials,
        int* __restrict__ counter,
        int B, int nblocks)
{
    __shared__ float lgpan[2][64 * 20];   // per-wave 5 KiB log panel
    __shared__ float redf[2][4];
    __shared__ double redd[2][4];
    __shared__ int amLast;

    const int tid  = threadIdx.x;
    const int lane = tid & 63;
    const int wv   = tid >> 6;
    float* pan = lgpan[wv];

    const int nchunks = (B + 63) >> 6;
    const int W = nblocks << 1;                  // total waves
    const int wid = (blockIdx.x << 1) + wv;
    const int ch0 = wid * 2, ch1 = wid * 2 + 1;
    const bool has0 = ch0 < nchunks, has1 = ch1 < nchunks;
    const int base0 = ch0 << 6, base1 = ch1 << 6;
    const bool full0 = has0 && (base0 + 64 <= B);
    const bool full1 = has1 && (base1 + 64 <= B);
    const bool inb0  = has0 && (full0 || base0 + lane < B);
    const bool inb1  = has1 && (full1 || base1 + lane < B);

    float ent = 0.f, uniq = 0.f, corr = 0.f, rloo = 0.f;
    float4 v0[5], v1[5];
    Samp sm0, sm1;

    if (has0) load_pcs(pCS, base0, B, full0, v0, lane);
    load_samp(sm0, Y, s1g, s2g, B, base0 + lane, inb0);
    if (has1) load_pcs(pCS, base1, B, full1, v1, lane);

    if (has0) ent += ent_write(pan, v0, lane);
    load_samp(sm1, Y, s1g, s2g, B, base1 + lane, inb1);
    __builtin_amdgcn_wave_barrier();
    body(pan, sm0, inb0, lane, uniq, corr, rloo);
    __builtin_amdgcn_wave_barrier();

    chunk(pan, v1, sm1, has1, inb1, lane, ent, uniq, corr, rloo);

    // leftover chunks beyond 2/wave (64 of them at B=1M, handled by wid<64)
    for (int ch = 2 * W + wid; ch < nchunks; ch += W) {
        const int base = ch << 6;
        const bool full = (base + 64) <= B;
        const bool inb  = full || (base + lane < B);
        float4 v[5]; Samp sm;
        load_pcs(pCS, base, B, full, v, lane);
        load_samp(sm, Y, s1g, s2g, B, base + lane, inb);
        chunk(pan, v, sm, true, inb, lane, ent, uniq, corr, rloo);
    }

    // ---- 64-lane butterfly ----
    #pragma unroll
    for (int off = 32; off >= 1; off >>= 1) {
        ent  += __shfl_xor(ent,  off);
        uniq += __shfl_xor(uniq, off);
        corr += __shfl_xor(corr, off);
        rloo += __shfl_xor(rloo, off);
    }

    if (lane == 0) {
        redf[wv][0] = ent; redf[wv][1] = uniq;
        redf[wv][2] = corr; redf[wv][3] = rloo;
    }
    __syncthreads();
    if (tid == 0) {
        float4 p;
        p.x = redf[0][0] + redf[1][0];
        p.y = redf[0][1] + redf[1][1];
        p.z = redf[0][2] + redf[1][2];
        p.w = redf[0][3] + redf[1][3];
        partials[blockIdx.x] = p;
        __threadfence();                           // release partials (device scope)
        int old = atomicAdd(counter, 1);
        amLast = (old == nblocks - 1) ? 1 : 0;
    }
    __syncthreads();

    if (amLast) {                                  // uniform per block
        __threadfence();                           // acquire all blocks' partials
        double e = 0, u = 0, cs = 0, rl = 0;
        for (int i = tid; i < nblocks; i += 128) {
            const volatile float* q = (const volatile float*)&partials[i];
            e += (double)q[0]; u += (double)q[1];
            cs += (double)q[2]; rl += (double)q[3];
        }
        #pragma unroll
        for (int off = 32; off >= 1; off >>= 1) {
            e  += __shfl_xor(e,  off);
            u  += __shfl_xor(u,  off);
            cs += __shfl_xor(cs, off);
            rl += __shfl_xor(rl, off);
        }
        if (lane == 0) { redd[wv][0] = e; redd[wv][1] = u; redd[wv][2] = cs; redd[wv][3] = rl; }
        __syncthreads();
        if (tid == 0) {
            e  = redd[0][0] + redd[1][0];
            u  = redd[0][1] + redd[1][1];
            cs = redd[0][2] + redd[1][2];
            rl = redd[0][3] + redd[1][3];
            const double dB = (double)B;
            const float entropy_loss = (float)(e / (2.0 * dB));   // = -(ent1+ent2)/2
            const float diversity = (float)(u / dB);
            const float ratio = diversity / 8.0f;                 // max_diversity = 8
            const float diversity_loss = -logf(ratio + EPSF);
            const float sample_acc = (float)(cs / (dB * (double)S_CONST));
            const float rloo_loss  = (float)(-rl / (dB * (double)S_CONST));
            out[0] = base_loss[0] + 0.01f * entropy_loss + 0.1f * diversity_loss;
            out[1] = rloo_loss;
            out[2] = diversity_loss;
            out[3] = sample_acc;
        }
    }
}

extern "C" void kernel_launch(void* const* d_in, const int* in_sizes, int n_in,
                              void* d_out, int out_size, void* d_ws, size_t ws_size,
                              hipStream_t stream) {
    const float* pCS       = (const float*)d_in[0];
    const float* base_loss = (const float*)d_in[1];
    const int*   Y         = (const int*)d_in[2];
    const int*   s1        = (const int*)d_in[3];
    const int*   s2        = (const int*)d_in[4];
    float* out = (float*)d_out;
    const int B = in_sizes[2];

    const int nchunks = (B + 63) >> 6;
    int blocks = (((nchunks + 1) >> 1) + 1) >> 1;      // ceil(waves/2), waves=ceil(nchunks/2)
    if (blocks > MAXBLK) blocks = MAXBLK;
    if (blocks < 1) blocks = 1;

    float4* partials = (float4*)d_ws;                  // blocks * 16 B
    int* counter = (int*)((char*)d_ws + (size_t)MAXBLK * sizeof(float4));

    hipMemsetAsync(counter, 0, sizeof(int), stream);   // fresh epoch every launch
    fml_fused<<<blocks, 128, 0, stream>>>(pCS, Y, s1, s2, base_loss, out,
                                          partials, counter, B, blocks);
}

// Round 7
// 42.214 us; speedup vs baseline: 3.4514x; 3.4514x over previous
//
#include <hip/hip_runtime.h>

#define S_CONST 8
#define EPSF 1e-8f

// fused log + entropy + gather-select for one element j of one head
__device__ __forceinline__ void elem(int j, float p, const int a[S_CONST],
                                     float g[S_CONST], float& ent) {
    const float lg = __logf(p);
    ent += p * lg;
    #pragma unroll
    for (int s = 0; s < S_CONST; ++s) g[s] = (a[s] == j) ? lg : g[s];
}

// partials[nblocks]: float4 {ent, uniq, corr, rloo}
__global__ __launch_bounds__(256) void fml_rows(
        const float* __restrict__ pCS,
        const int* __restrict__ Y,
        const int* __restrict__ s1g,
        const int* __restrict__ s2g,
        float4* __restrict__ partials,
        int B)
{
    float ent = 0.f, uniq = 0.f, corr = 0.f, rloo = 0.f;

    const int gid = blockIdx.x * 256 + threadIdx.x;
    const int gstride = gridDim.x * 256;

    #pragma unroll 1          // no unroll: keep VGPR <= 64, TLP hides latency
    for (int row = gid; row < B; row += gstride) {
        // ---- issue all loads up front: own row (80B) + y + 16 samples ----
        const float4* rp = reinterpret_cast<const float4*>(pCS + (size_t)row * 20);
        const float4 v0 = rp[0], v1 = rp[1], v2 = rp[2], v3 = rp[3], v4 = rp[4];
        const int y = Y[row];
        int a1[S_CONST], a2[S_CONST];
        #pragma unroll
        for (int s = 0; s < S_CONST; ++s) {
            a1[s] = s1g[(size_t)s * B + row];
            a2[s] = s2g[(size_t)s * B + row];
        }

        // ---- correct / advantage ----
        float c[S_CONST], csum = 0.f;
        #pragma unroll
        for (int s = 0; s < S_CONST; ++s) {
            c[s] = (a1[s] + a2[s] == y) ? 1.f : 0.f;
            csum += c[s];
        }
        corr += csum;

        // ---- unique count via pair codes (codes die before log phase) ----
        {
            int pr[S_CONST];
            #pragma unroll
            for (int s = 0; s < S_CONST; ++s) pr[s] = a1[s] * 10 + a2[s];
            #pragma unroll
            for (int i = 0; i < S_CONST; ++i) {
                bool dup = false;
                #pragma unroll
                for (int j = 0; j < i; ++j) dup = dup || (pr[i] == pr[j]);
                uniq += dup ? 0.f : 1.f;
            }
        }

        float adv[S_CONST];
        #pragma unroll
        for (int s = 0; s < S_CONST; ++s)
            adv[s] = c[s] * (8.0f / 7.0f) - csum * (1.0f / 7.0f);  // c-(csum-c)/7

        // ---- head 1: elements 0..9 = v0.xyzw v1.xyzw v2.xy ----
        float g1[S_CONST];
        #pragma unroll
        for (int s = 0; s < S_CONST; ++s) g1[s] = 0.f;
        elem(0, v0.x, a1, g1, ent); elem(1, v0.y, a1, g1, ent);
        elem(2, v0.z, a1, g1, ent); elem(3, v0.w, a1, g1, ent);
        elem(4, v1.x, a1, g1, ent); elem(5, v1.y, a1, g1, ent);
        elem(6, v1.z, a1, g1, ent); elem(7, v1.w, a1, g1, ent);
        elem(8, v2.x, a1, g1, ent); elem(9, v2.y, a1, g1, ent);
        // fold head1 into rloo now so g1/a1 die before head2
        #pragma unroll
        for (int s = 0; s < S_CONST; ++s) rloo += g1[s] * adv[s];

        // ---- head 2: elements 0..9 = v2.zw v3.xyzw v4.xyzw ----
        float g2[S_CONST];
        #pragma unroll
        for (int s = 0; s < S_CONST; ++s) g2[s] = 0.f;
        elem(0, v2.z, a2, g2, ent); elem(1, v2.w, a2, g2, ent);
        elem(2, v3.x, a2, g2, ent); elem(3, v3.y, a2, g2, ent);
        elem(4, v3.z, a2, g2, ent); elem(5, v3.w, a2, g2, ent);
        elem(6, v4.x, a2, g2, ent); elem(7, v4.y, a2, g2, ent);
        elem(8, v4.z, a2, g2, ent); elem(9, v4.w, a2, g2, ent);
        #pragma unroll
        for (int s = 0; s < S_CONST; ++s) rloo += g2[s] * adv[s];
    }

    // ---- 64-lane butterfly ----
    #pragma unroll
    for (int off = 32; off >= 1; off >>= 1) {
        ent  += __shfl_xor(ent,  off);
        uniq += __shfl_xor(uniq, off);
        corr += __shfl_xor(corr, off);
        rloo += __shfl_xor(rloo, off);
    }

    __shared__ float red[4][4];
    const int lane = threadIdx.x & 63;
    const int wv   = threadIdx.x >> 6;
    if (lane == 0) {
        red[wv][0] = ent; red[wv][1] = uniq;
        red[wv][2] = corr; red[wv][3] = rloo;
    }
    __syncthreads();
    if (threadIdx.x == 0) {
        float4 p;
        p.x = red[0][0] + red[1][0] + red[2][0] + red[3][0];
        p.y = red[0][1] + red[1][1] + red[2][1] + red[3][1];
        p.z = red[0][2] + red[1][2] + red[2][2] + red[3][2];
        p.w = red[0][3] + red[1][3] + red[2][3] + red[3][3];
        partials[blockIdx.x] = p;
    }
}

__global__ __launch_bounds__(1024) void fml_finalize(
        const float4* __restrict__ partials,
        const float* __restrict__ base_loss,
        float* __restrict__ out, int B, int nblocks)
{
    __shared__ double red[16][4];
    double e = 0, u = 0, cs = 0, rl = 0;
    for (int i = threadIdx.x; i < nblocks; i += 1024) {
        const float4 p = partials[i];
        e += (double)p.x; u += (double)p.y; cs += (double)p.z; rl += (double)p.w;
    }
    #pragma unroll
    for (int off = 32; off >= 1; off >>= 1) {
        e  += __shfl_xor(e,  off);
        u  += __shfl_xor(u,  off);
        cs += __shfl_xor(cs, off);
        rl += __shfl_xor(rl, off);
    }
    const int lane = threadIdx.x & 63;
    const int wave = threadIdx.x >> 6;
    if (lane == 0) { red[wave][0] = e; red[wave][1] = u; red[wave][2] = cs; red[wave][3] = rl; }
    __syncthreads();
    if (threadIdx.x == 0) {
        e = 0; u = 0; cs = 0; rl = 0;
        #pragma unroll
        for (int w = 0; w < 16; ++w) {
            e += red[w][0]; u += red[w][1]; cs += red[w][2]; rl += red[w][3];
        }
        const double dB = (double)B;
        const float entropy_loss = (float)(e / (2.0 * dB));   // = -(ent1+ent2)/2
        const float diversity = (float)(u / dB);
        const float ratio = diversity / 8.0f;                 // max_diversity = 8
        const float diversity_loss = -logf(ratio + EPSF);
        const float sample_acc = (float)(cs / (dB * (double)S_CONST));
        const float rloo_loss  = (float)(-rl / (dB * (double)S_CONST));
        out[0] = base_loss[0] + 0.01f * entropy_loss + 0.1f * diversity_loss;
        out[1] = rloo_loss;
        out[2] = diversity_loss;
        out[3] = sample_acc;
    }
}

extern "C" void kernel_launch(void* const* d_in, const int* in_sizes, int n_in,
                              void* d_out, int out_size, void* d_ws, size_t ws_size,
                              hipStream_t stream) {
    const float* pCS       = (const float*)d_in[0];
    const float* base_loss = (const float*)d_in[1];
    const int*   Y         = (const int*)d_in[2];
    const int*   s1        = (const int*)d_in[3];
    const int*   s2        = (const int*)d_in[4];
    float* out = (float*)d_out;
    const int B = in_sizes[2];

    float4* partials = (float4*)d_ws;     // 2048 * 16 B = 32 KB (well under ws)

    const int grid = 2048;                // 8 blocks/CU; 2 rows/lane at B=1M
    fml_rows<<<grid, 256, 0, stream>>>(pCS, Y, s1, s2, partials, B);
    fml_finalize<<<1, 1024, 0, stream>>>(partials, base_loss, out, B, grid);
}